// Round 12
// baseline (287.193 us; speedup 1.0000x reference)
//
#include <hip/hip_runtime.h>

typedef unsigned short u16;
typedef unsigned int u32;

#define S 2048
#define HID 2048
#define NH 16
#define NKV 4
#define D 128
#define QKVP 3072  // QKV buffer pitch (Q|K|V concat per row)
// 1/sqrt(128) * log2(e): scores come out of QK^T already in log2 domain
#define QSCALE (0.08838834764831845f * 1.4426950408889634f)
#define NEG_INF -3.0e38f

typedef __attribute__((ext_vector_type(8))) short short8;  // 8 bf16 = 4 VGPRs
typedef __attribute__((ext_vector_type(4))) float f32x4;

__device__ __forceinline__ float bf2f(u16 u) {
  union { u32 i; float f; } c; c.i = ((u32)u) << 16; return c.f;
}
__device__ __forceinline__ u16 f2bf(float f) {
  union { float f; u32 i; } c; c.f = f;
  u32 x = c.i;
  u32 r = x + 0x7fffu + ((x >> 16) & 1u);  // RNE
  return (u16)(r >> 16);
}

#if __has_builtin(__builtin_amdgcn_exp2f)
__device__ __forceinline__ float exp2_hw(float x) { return __builtin_amdgcn_exp2f(x); }
#else
__device__ __forceinline__ float exp2_hw(float x) { return exp2f(x); }
#endif

// packed f32x2 -> bf16x2 (RNE), single VOP3
__device__ __forceinline__ u32 cvt_pk_bf16(float a, float b) {
  u32 r;
  asm("v_cvt_pk_bf16_f32 %0, %1, %2" : "=v"(r) : "v"(a), "v"(b));
  return r;
}

__device__ __forceinline__ void gload16(const u16* g, u16* l) {
  __builtin_amdgcn_global_load_lds(
      (const __attribute__((address_space(1))) u32*)g,
      (__attribute__((address_space(3))) u32*)l, 16, 0, 0);
}

// ------- transpose + convert body: src[K][N] f32 -> dst[N][K] bf16 ----------
__device__ __forceinline__ void transpose_body(const float* __restrict__ src,
                                               u16* __restrict__ dst,
                                               int N, int K, int nt, int kt,
                                               int t) {
  __shared__ float T[64][65];
#pragma unroll
  for (int it = 0; it < 4; ++it) {
    int r = it * 16 + (t >> 4), c = (t & 15) * 4;
    float4 v = *(const float4*)(src + (size_t)(kt + r) * N + nt + c);
    T[r][c] = v.x; T[r][c + 1] = v.y; T[r][c + 2] = v.z; T[r][c + 3] = v.w;
  }
  __syncthreads();
#pragma unroll
  for (int it = 0; it < 2; ++it) {
    int n = it * 32 + (t >> 3), k8 = (t & 7) * 8;
    ushort4 w0, w1;
    w0.x = f2bf(T[k8 + 0][n]); w0.y = f2bf(T[k8 + 1][n]);
    w0.z = f2bf(T[k8 + 2][n]); w0.w = f2bf(T[k8 + 3][n]);
    w1.x = f2bf(T[k8 + 4][n]); w1.y = f2bf(T[k8 + 5][n]);
    w1.z = f2bf(T[k8 + 6][n]); w1.w = f2bf(T[k8 + 7][n]);
    *(ushort4*)(dst + (size_t)(nt + n) * K + kt + k8) = w0;
    *(ushort4*)(dst + (size_t)(nt + n) * K + kt + k8 + 4) = w1;
  }
}

// ------- merged preprocessing: hidden f32->bf16 cvt + Wq|Wk|Wv transpose ----
__global__ __launch_bounds__(256) void k_pre(const float* __restrict__ hidden,
                                             u16* __restrict__ Hb,
                                             const float* __restrict__ Wq,
                                             const float* __restrict__ Wk,
                                             const float* __restrict__ Wv,
                                             u16* __restrict__ WT) {
  const int bx = blockIdx.x, t = threadIdx.x;
  if (bx < 2048) {  // cvt: 2048 blocks x 2048 elems
    int i = (bx * 256 + t) * 8;
    float4 v0 = *(const float4*)(hidden + i);
    float4 v1 = *(const float4*)(hidden + i + 4);
    ushort4 w0, w1;
    w0.x = f2bf(v0.x); w0.y = f2bf(v0.y); w0.z = f2bf(v0.z); w0.w = f2bf(v0.w);
    w1.x = f2bf(v1.x); w1.y = f2bf(v1.y); w1.z = f2bf(v1.z); w1.w = f2bf(v1.w);
    *(ushort4*)(Hb + i) = w0;
    *(ushort4*)(Hb + i + 4) = w1;
    return;
  }
  const int id = bx - 2048;            // 0..1535
  const int x = id % 48, y = id / 48;  // old dim3(48,32)
  const float* src; u16* dst; int N, nt;
  if (x < 32)      { src = Wq; dst = WT;                    N = 2048; nt = x * 64; }
  else if (x < 40) { src = Wk; dst = WT + 2048ull * 2048;   N = 512;  nt = (x - 32) * 64; }
  else             { src = Wv; dst = WT + 2560ull * 2048;   N = 512;  nt = (x - 40) * 64; }
  transpose_body(src, dst, N, 2048, nt, y * 64, t);
}

__global__ __launch_bounds__(256) void k_transpose(const float* __restrict__ src,
                                                   u16* __restrict__ dst,
                                                   int N, int K) {
  transpose_body(src, dst, N, K, blockIdx.x * 64, blockIdx.y * 64, threadIdx.x);
}

// ------- QKV GEMM with FUSED epilogue: norm+RoPE (Q/K) or Vt write (V) ------
// BN=128 spans exactly one head (D=128): each block holds full head rows in
// registers at epilogue. Q/K blocks (n0<2560): RMSNorm on f32 accumulators
// (shfl-over-l15 + 1KB LDS cross-wave reduce), RoPE partner (d^64) fetched
// through a 33KB LDS tile carved from the dead staging buffers -> replaces
// the whole norm_rope pass. V blocks: registers -> Vt directly (replaces
// k_vt); QKV V-section store dropped (nothing reads it).
// Main loop = R11-proven reads-first BK=64 XOR-swizzle structure.
__global__ __launch_bounds__(256) void k_gemm_qkv(const u16* __restrict__ A,
                                                  const u16* __restrict__ BT,
                                                  u16* __restrict__ QKV,
                                                  u16* __restrict__ Vt,
                                                  const float* __restrict__ qsc,
                                                  const float* __restrict__ ksc,
                                                  const float* __restrict__ cosp,
                                                  const float* __restrict__ sinp) {
  __shared__ __align__(16) char smem[49152];
  u16* AsB = (u16*)smem;            // [2][64*64]
  u16* BsB = (u16*)(smem + 16384);  // [2][128*64]
  const int K = 2048;
  const int t = threadIdx.x, w = t >> 6, lane = t & 63;
  const int l15 = lane & 15, quad = lane >> 4;
  const int m0 = blockIdx.y * 64, n0 = blockIdx.x * 128;

  const int srow = lane >> 3;                       // 0..7 within issue
  const int schunk = (lane & 7) ^ srow;             // pre-swizzled source chunk
  const u16* Agb = A + (size_t)(m0 + w * 8 + srow) * K + schunk * 8;
  const u16* Bgb = BT + (size_t)(n0 + w * 8 + srow) * K + schunk * 8;

  f32x4 acc[4][2];
#pragma unroll
  for (int i = 0; i < 4; ++i)
#pragma unroll
    for (int j = 0; j < 2; ++j) acc[i][j] = (f32x4){0.f, 0.f, 0.f, 0.f};

  auto STAGE = [&](int k0, int b) {
#pragma unroll
    for (int it = 0; it < 2; ++it)
      gload16(Agb + (size_t)it * 32 * K + k0, AsB + b * 4096 + (w * 8 + it * 32) * 64);
#pragma unroll
    for (int it = 0; it < 4; ++it)
      gload16(Bgb + (size_t)it * 32 * K + k0, BsB + b * 8192 + (w * 8 + it * 32) * 64);
  };

  STAGE(0, 0);
  __syncthreads();  // buf0 ready
  int cur = 0;
  for (int k0 = 0; k0 < K; k0 += 64) {
    short8 af[4][2], bf[2][2];
#pragma unroll
    for (int k2 = 0; k2 < 2; ++k2) {
      int ch = (k2 * 4 + quad) ^ (l15 & 7);
#pragma unroll
      for (int i = 0; i < 4; ++i)
        af[i][k2] = *(const short8*)&AsB[cur * 4096 + (i * 16 + l15) * 64 + ch * 8];
#pragma unroll
      for (int j = 0; j < 2; ++j)
        bf[j][k2] = *(const short8*)&BsB[cur * 8192 + (w * 32 + j * 16 + l15) * 64 + ch * 8];
    }

    if (k0 + 64 < K) STAGE(k0 + 64, cur ^ 1);  // DMA flies under the MFMAs

#pragma unroll
    for (int k2 = 0; k2 < 2; ++k2)
#pragma unroll
      for (int i = 0; i < 4; ++i)
#pragma unroll
        for (int j = 0; j < 2; ++j)
          acc[i][j] = __builtin_amdgcn_mfma_f32_16x16x32_bf16(af[i][k2], bf[j][k2], acc[i][j], 0, 0, 0);

    __syncthreads();  // drains prefetch + all waves done reading cur
    cur ^= 1;
  }

  // ---------------- fused epilogue ----------------
  const int colL0 = w * 32 + l15;        // j=0 local col
  const int colL1 = w * 32 + 16 + l15;   // j=1 local col

  if (n0 < 2560) {  // Q or K head: RMSNorm + RoPE on f32 accumulators
    const float* sc = (n0 < 2048) ? qsc : ksc;
    const float scale = (n0 < 2048) ? QSCALE : 1.0f;

    // per-row sum of squares: partial over this thread's 2 cols
    float ssp[4][4];
#pragma unroll
    for (int i = 0; i < 4; ++i)
#pragma unroll
      for (int r = 0; r < 4; ++r)
        ssp[i][r] = acc[i][0][r] * acc[i][0][r] + acc[i][1][r] * acc[i][1][r];
    // reduce over the 16 l15 lanes (stays within quad group)
#pragma unroll
    for (int o = 1; o < 16; o <<= 1)
#pragma unroll
      for (int i = 0; i < 4; ++i)
#pragma unroll
        for (int r = 0; r < 4; ++r) ssp[i][r] += __shfl_xor(ssp[i][r], o, 64);
    // cross-wave via LDS (staging buffers dead after final loop barrier)
    float* red = (float*)smem;           // 256 f32
    float* X = (float*)(smem + 2048);    // [64][132] f32, 33.8KB
    if (l15 == 0) {
#pragma unroll
      for (int i = 0; i < 4; ++i)
#pragma unroll
        for (int r = 0; r < 4; ++r) red[w * 64 + i * 16 + quad * 4 + r] = ssp[i][r];
    }
    __syncthreads();
    float rinv[4][4];
#pragma unroll
    for (int i = 0; i < 4; ++i)
#pragma unroll
      for (int r = 0; r < 4; ++r) {
        int row = i * 16 + quad * 4 + r;
        float s = red[row] + red[64 + row] + red[128 + row] + red[192 + row];
        rinv[i][r] = rsqrtf(s * (1.0f / 128.0f) + 1e-6f) * scale;
      }
    float sc0 = sc[colL0], sc1 = sc[colL1];
#pragma unroll
    for (int i = 0; i < 4; ++i)
#pragma unroll
      for (int r = 0; r < 4; ++r) {
        int row = i * 16 + quad * 4 + r;
        X[row * 132 + colL0] = acc[i][0][r] * rinv[i][r] * sc0;
        X[row * 132 + colL1] = acc[i][1][r] * rinv[i][r] * sc1;
      }
    __syncthreads();
    // RoPE: partner col = d ^ 64
    float sgn0 = (colL0 < 64) ? -1.f : 1.f;
    float sgn1 = (colL1 < 64) ? -1.f : 1.f;
#pragma unroll
    for (int i = 0; i < 4; ++i)
#pragma unroll
      for (int r = 0; r < 4; ++r) {
        int row = i * 16 + quad * 4 + r;
        int srw = m0 + row;
        float xn0 = X[row * 132 + colL0], p0 = X[row * 132 + (colL0 ^ 64)];
        float xn1 = X[row * 132 + colL1], p1 = X[row * 132 + (colL1 ^ 64)];
        float v0 = xn0 * cosp[srw * D + colL0] + sgn0 * p0 * sinp[srw * D + colL0];
        float v1 = xn1 * cosp[srw * D + colL1] + sgn1 * p1 * sinp[srw * D + colL1];
        QKV[(size_t)srw * QKVP + n0 + colL0] = f2bf(v0);
        QKV[(size_t)srw * QKVP + n0 + colL1] = f2bf(v1);
      }
  } else {  // V head: write transposed Vt[gd][s] directly (skip QKV store)
#pragma unroll
    for (int i = 0; i < 4; ++i) {
      int sbase = m0 + i * 16 + quad * 4;
      ushort4 w0, w1;
      w0.x = f2bf(acc[i][0][0]); w0.y = f2bf(acc[i][0][1]);
      w0.z = f2bf(acc[i][0][2]); w0.w = f2bf(acc[i][0][3]);
      w1.x = f2bf(acc[i][1][0]); w1.y = f2bf(acc[i][1][1]);
      w1.z = f2bf(acc[i][1][2]); w1.w = f2bf(acc[i][1][3]);
      *(ushort4*)(Vt + (size_t)(n0 - 2560 + colL0) * S + sbase) = w0;
      *(ushort4*)(Vt + (size_t)(n0 - 2560 + colL1) * S + sbase) = w1;
    }
  }
}

// ------- MFMA GEMM (Wo): BM=64 x BN=128, BK=64, reads-first, XOR swizzle ----
__global__ __launch_bounds__(256) void k_gemm_mfma(const u16* __restrict__ A,
                                                   const u16* __restrict__ BT,
                                                   void* __restrict__ Cout,
                                                   int N, int K, int out_bf16) {
  __shared__ __align__(16) u16 As[2][64 * 64];
  __shared__ __align__(16) u16 Bs[2][128 * 64];
  const int t = threadIdx.x, w = t >> 6, lane = t & 63;
  const int l15 = lane & 15, quad = lane >> 4;
  const int m0 = blockIdx.y * 64, n0 = blockIdx.x * 128;

  const int srow = lane >> 3;                       // 0..7 within issue
  const int schunk = (lane & 7) ^ srow;             // pre-swizzled source chunk
  const u16* Agb = A + (size_t)(m0 + w * 8 + srow) * K + schunk * 8;
  const u16* Bgb = BT + (size_t)(n0 + w * 8 + srow) * K + schunk * 8;

  f32x4 acc[4][2];
#pragma unroll
  for (int i = 0; i < 4; ++i)
#pragma unroll
    for (int j = 0; j < 2; ++j) acc[i][j] = (f32x4){0.f, 0.f, 0.f, 0.f};

  auto STAGE = [&](int k0, int b) {
#pragma unroll
    for (int it = 0; it < 2; ++it)
      gload16(Agb + (size_t)it * 32 * K + k0, &As[b][(w * 8 + it * 32) * 64]);
#pragma unroll
    for (int it = 0; it < 4; ++it)
      gload16(Bgb + (size_t)it * 32 * K + k0, &Bs[b][(w * 8 + it * 32) * 64]);
  };

  STAGE(0, 0);
  __syncthreads();  // buf0 ready
  int cur = 0;
  for (int k0 = 0; k0 < K; k0 += 64) {
    short8 af[4][2], bf[2][2];
#pragma unroll
    for (int k2 = 0; k2 < 2; ++k2) {
      int ch = (k2 * 4 + quad) ^ (l15 & 7);
#pragma unroll
      for (int i = 0; i < 4; ++i)
        af[i][k2] = *(const short8*)&As[cur][(i * 16 + l15) * 64 + ch * 8];
#pragma unroll
      for (int j = 0; j < 2; ++j)
        bf[j][k2] = *(const short8*)&Bs[cur][(w * 32 + j * 16 + l15) * 64 + ch * 8];
    }

    if (k0 + 64 < K) STAGE(k0 + 64, cur ^ 1);  // DMA flies under the MFMAs

#pragma unroll
    for (int k2 = 0; k2 < 2; ++k2)
#pragma unroll
      for (int i = 0; i < 4; ++i)
#pragma unroll
        for (int j = 0; j < 2; ++j)
          acc[i][j] = __builtin_amdgcn_mfma_f32_16x16x32_bf16(af[i][k2], bf[j][k2], acc[i][j], 0, 0, 0);

    __syncthreads();  // drains prefetch + all waves done reading cur
    cur ^= 1;
  }

  if (out_bf16) {
    u16* C = (u16*)Cout;
#pragma unroll
    for (int i = 0; i < 4; ++i)
#pragma unroll
      for (int j = 0; j < 2; ++j) {
        int col = n0 + w * 32 + j * 16 + l15;
#pragma unroll
        for (int r = 0; r < 4; ++r)
          C[(size_t)(m0 + i * 16 + quad * 4 + r) * N + col] = f2bf(acc[i][j][r]);
      }
  } else {
    float* C = (float*)Cout;
#pragma unroll
    for (int i = 0; i < 4; ++i)
#pragma unroll
      for (int j = 0; j < 2; ++j) {
        int col = n0 + w * 32 + j * 16 + l15;
#pragma unroll
        for (int r = 0; r < 4; ++r)
          C[(size_t)(m0 + i * 16 + quad * 4 + r) * N + col] = acc[i][j][r];
      }
  }
}

// ---------------- flash attention (R10-frozen) ------------------------------
#define KP 128   // K LDS row pitch (u16), unpadded (DMA requirement)
#define PTP 72   // P pitch (u16): b64-write / b128-read aligned

__global__ __launch_bounds__(256) void k_flash(const u16* __restrict__ QKV,
                                               const u16* __restrict__ Vt,
                                               u16* __restrict__ O) {
  const int h = blockIdx.y, g = h >> 2;
  const int qt = (h < 8) ? (31 - (int)blockIdx.x) : (int)blockIdx.x;
  const int t = threadIdx.x;
  const int w = t >> 6, lane = t & 63, l15 = lane & 15, quad = lane >> 4;

  __shared__ __align__(16) u16 Klds[2][64 * KP];
  __shared__ __align__(16) u16 Vlds[128 * 64];     // [d][key], XOR-swizzled
  __shared__ __align__(16) u16 Pt[4][16 * PTP];    // [qcol][key] per wave

  const int qbase = qt * 64 + w * 16;
  const int qrow = qbase + l15;

  short8 qf[4];
  {
    const u16* qp = QKV + (size_t)qrow * QKVP + h * D + quad * 8;
#pragma unroll
    for (int c = 0; c < 4; ++c) qf[c] = *(const short8*)(qp + c * 32);
  }

  float m = NEG_INF, l = 0.f;
  f32x4 oacc[8];
#pragma unroll
  for (int nc = 0; nc < 8; ++nc) oacc[nc] = (f32x4){0.f, 0.f, 0.f, 0.f};

  const int nt = qt + 1;
  const int dd = t >> 3, cc = t & 7;  // V staging coords

  auto KLOAD = [&](int j0, int b) {  // DMA 4 rows per wave per issue
#pragma unroll
    for (int it = 0; it < 4; ++it) {
      int rl = w * 16 + it * 4 + quad;                 // tile-local key row
      int gchunk = (lane & 15) ^ (rl & 7);             // source swizzle
      const u16* gp = QKV + (size_t)(j0 + rl) * QKVP + 2048 + g * D + gchunk * 8;
      gload16(gp, &Klds[b][(w * 16 + it * 4) * KP]);
    }
  };
  auto VLOAD = [&](int j0, uint4* vr) {
#pragma unroll
    for (int it = 0; it < 4; ++it)
      vr[it] = *(const uint4*)(Vt + (size_t)(g * D + dd + it * 32) * S + j0 + cc * 8);
  };
  auto VWRITE = [&](uint4* vr) {
#pragma unroll
    for (int it = 0; it < 4; ++it) {
      int d = dd + it * 32;
      *(uint4*)&Vlds[d * 64 + ((cc ^ (d & 7)) * 8)] = vr[it];
    }
  };
  auto QKT = [&](int b, f32x4* sa) {
#pragma unroll
    for (int sub = 0; sub < 4; ++sub) {
      f32x4 acc = {0.f, 0.f, 0.f, 0.f};
#pragma unroll
      for (int c = 0; c < 4; ++c) {
        int ch = (c * 4 + quad) ^ (l15 & 7);  // undo source swizzle
        short8 kf = *(const short8*)&Klds[b][(sub * 16 + l15) * KP + ch * 8];
        acc = __builtin_amdgcn_mfma_f32_16x16x32_bf16(kf, qf[c], acc, 0, 0, 0);
      }
      sa[sub] = acc;
    }
  };
  auto SMPV = [&](int jt, f32x4* sa) {
    const int j0 = jt * 64;
    if (jt == nt - 1) {  // causal mask, diagonal tile only
#pragma unroll
      for (int sub = 0; sub < 4; ++sub) {
        int keyb = j0 + sub * 16 + quad * 4;
#pragma unroll
        for (int r = 0; r < 4; ++r)
          if (keyb + r > qrow) sa[sub][r] = NEG_INF;
      }
    }
    float tmax = sa[0][0];
#pragma unroll
    for (int sub = 0; sub < 4; ++sub)
#pragma unroll
      for (int r = 0; r < 4; ++r) tmax = fmaxf(tmax, sa[sub][r]);
    tmax = fmaxf(tmax, __shfl_xor(tmax, 16, 64));
    tmax = fmaxf(tmax, __shfl_xor(tmax, 32, 64));
    float mn = fmaxf(m, tmax);
    float alpha = exp2_hw(m - mn);
    m = mn;
    float rs = 0.f;
#pragma unroll
    for (int sub = 0; sub < 4; ++sub) {
      float p0 = exp2_hw(sa[sub][0] - m);
      float p1 = exp2_hw(sa[sub][1] - m);
      float p2 = exp2_hw(sa[sub][2] - m);
      float p3 = exp2_hw(sa[sub][3] - m);
      rs += (p0 + p1) + (p2 + p3);
      u32 lo = cvt_pk_bf16(p0, p1);
      u32 hi = cvt_pk_bf16(p2, p3);
      *(uint2*)&Pt[w][l15 * PTP + sub * 16 + quad * 4] = make_uint2(lo, hi);
    }
    rs += __shfl_xor(rs, 16, 64);
    rs += __shfl_xor(rs, 32, 64);
    l = l * alpha + rs;
#pragma unroll
    for (int nc = 0; nc < 8; ++nc) {
      oacc[nc][0] *= alpha; oacc[nc][1] *= alpha;
      oacc[nc][2] *= alpha; oacc[nc][3] *= alpha;
    }
#pragma unroll
    for (int kc = 0; kc < 2; ++kc) {
      short8 pf = *(const short8*)&Pt[w][l15 * PTP + kc * 32 + quad * 8];
#pragma unroll
      for (int nc = 0; nc < 8; ++nc) {
        int d = nc * 16 + l15;
        short8 vf = *(const short8*)&Vlds[d * 64 + (((kc * 4 + quad) ^ (d & 7)) * 8)];
        oacc[nc] = __builtin_amdgcn_mfma_f32_16x16x32_bf16(vf, pf, oacc[nc], 0, 0, 0);
      }
    }
  };

  uint4 vrA[4], vrB[4];
  f32x4 sa[4];
  KLOAD(0, 0);
  VLOAD(0, vrA);
  for (int jt = 0; jt < nt; jt += 2) {
    __syncthreads();                       // drains K(jt) DMA + all VMEM
    VWRITE(vrA);
    __syncthreads();                       // V(jt) visible
    QKT(0, sa);                            // no outstanding VMEM -> no stall
    if (jt + 1 < nt) { KLOAD((jt + 1) * 64, 1); VLOAD((jt + 1) * 64, vrB); }
    SMPV(jt, sa);                          // covers prefetch latency
    if (jt + 1 < nt) {
      __syncthreads();                     // drains K(jt+1)+V(jt+1), covered
      VWRITE(vrB);
      __syncthreads();
      QKT(1, sa);
      if (jt + 2 < nt) { KLOAD((jt + 2) * 64, 0); VLOAD((jt + 2) * 64, vrA); }
      SMPV(jt + 1, sa);
    }
  }

  // ---- epilogue: O[q][d] = O^T / l ----
  float inv = 1.0f / l;
  u16* orow = O + (size_t)qrow * HID + h * D;
#pragma unroll
  for (int nc = 0; nc < 8; ++nc) {
    ushort4 wv;
    wv.x = f2bf(oacc[nc][0] * inv); wv.y = f2bf(oacc[nc][1] * inv);
    wv.z = f2bf(oacc[nc][2] * inv); wv.w = f2bf(oacc[nc][3] * inv);
    *(ushort4*)(orow + nc * 16 + quad * 4) = wv;
  }
}

// ---------------- final RMSNorm over HIDDEN=2048 ----------------------------
__device__ __forceinline__ float blockSum256(float v, float* red, int t) {
#pragma unroll
  for (int o = 32; o; o >>= 1) v += __shfl_xor(v, o, 64);
  if ((t & 63) == 0) red[t >> 6] = v;
  __syncthreads();
  v = red[0] + red[1] + red[2] + red[3];
  __syncthreads();
  return v;
}

__global__ __launch_bounds__(256) void k_fnorm(const float* __restrict__ X,
                                               const float* __restrict__ sc,
                                               float* __restrict__ out) {
  const int s = blockIdx.x, t = threadIdx.x;
  const float* row = X + (size_t)s * HID;
  float4 r0 = *(const float4*)(row + t * 8);
  float4 r1 = *(const float4*)(row + t * 8 + 4);
  float x[8] = {r0.x, r0.y, r0.z, r0.w, r1.x, r1.y, r1.z, r1.w};
  float ss = 0.f;
#pragma unroll
  for (int ii = 0; ii < 8; ++ii) ss += x[ii] * x[ii];
  __shared__ float red[4];
  float tot = blockSum256(ss, red, t);
  float rinv = rsqrtf(tot * (1.0f / 2048.0f) + 1e-6f);
  float4 s0 = *(const float4*)(sc + t * 8);
  float4 s1 = *(const float4*)(sc + t * 8 + 4);
  float4 w0 = make_float4(x[0] * rinv * s0.x, x[1] * rinv * s0.y,
                          x[2] * rinv * s0.z, x[3] * rinv * s0.w);
  float4 w1 = make_float4(x[4] * rinv * s1.x, x[5] * rinv * s1.y,
                          x[6] * rinv * s1.z, x[7] * rinv * s1.w);
  *(float4*)(out + (size_t)s * HID + t * 8) = w0;
  *(float4*)(out + (size_t)s * HID + t * 8 + 4) = w1;
}

extern "C" void kernel_launch(void* const* d_in, const int* in_sizes, int n_in,
                              void* d_out, int out_size, void* d_ws, size_t ws_size,
                              hipStream_t stream) {
  const float* hidden = (const float*)d_in[0];
  const float* cosp   = (const float*)d_in[1];
  const float* sinp   = (const float*)d_in[2];
  const float* Wq     = (const float*)d_in[3];
  const float* Wk     = (const float*)d_in[4];
  const float* Wv     = (const float*)d_in[5];
  const float* Wo     = (const float*)d_in[6];
  const float* qsc    = (const float*)d_in[7];
  const float* ksc    = (const float*)d_in[8];
  const float* lsc    = (const float*)d_in[9];
  float* out = (float*)d_out;

  char* ws = (char*)d_ws;
  u16*   Hb  = (u16*)(ws);                   // [S][HID] bf16, 8 MiB
  u16*   WoT = (u16*)(ws);                   // overlays Hb (after QKV GEMM)
  u16*   WT  = (u16*)(ws + (8ull << 20));    // [3072][2048] bf16, 12 MiB
  u16*   An  = (u16*)(ws + (8ull << 20));    // overlays WT (after QKV GEMM)
  u16*   QKV = (u16*)(ws + (20ull << 20));   // [S][3072] bf16, 12 MiB
  float* Ob  = (float*)(ws + (20ull << 20)); // overlays QKV (after flash)
  u16*   Vtb = (u16*)(ws + (32ull << 20));   // [512][2048] bf16, 2 MiB

  k_pre<<<2048 + 1536, 256, 0, stream>>>(hidden, Hb, Wq, Wk, Wv, WT);
  k_gemm_qkv<<<dim3(24, 32), 256, 0, stream>>>(Hb, WT, QKV, Vtb, qsc, ksc, cosp, sinp);
  k_transpose<<<dim3(32, 32), 256, 0, stream>>>(Wo, WoT, 2048, 2048);  // Hb dead
  k_flash<<<dim3(32, NH), 256, 0, stream>>>(QKV, Vtb, An);
  k_gemm_mfma<<<dim3(16, 32), 256, 0, stream>>>(An, WoT, Ob, 2048, 2048, 0);
  k_fnorm<<<S, 256, 0, stream>>>(Ob, lsc, out);
}

// Round 13
// 283.083 us; speedup vs baseline: 1.0145x; 1.0145x over previous
//
#include <hip/hip_runtime.h>

typedef unsigned short u16;
typedef unsigned int u32;

#define S 2048
#define HID 2048
#define NH 16
#define NKV 4
#define D 128
#define QKVP 3072  // QKV buffer pitch (Q|K|V concat per row)
// 1/sqrt(128) * log2(e): scores come out of QK^T already in log2 domain
#define QSCALE (0.08838834764831845f * 1.4426950408889634f)
#define NEG_INF -3.0e38f

typedef __attribute__((ext_vector_type(8))) short short8;  // 8 bf16 = 4 VGPRs
typedef __attribute__((ext_vector_type(4))) float f32x4;

__device__ __forceinline__ float bf2f(u16 u) {
  union { u32 i; float f; } c; c.i = ((u32)u) << 16; return c.f;
}
__device__ __forceinline__ u16 f2bf(float f) {
  union { float f; u32 i; } c; c.f = f;
  u32 x = c.i;
  u32 r = x + 0x7fffu + ((x >> 16) & 1u);  // RNE
  return (u16)(r >> 16);
}

#if __has_builtin(__builtin_amdgcn_exp2f)
__device__ __forceinline__ float exp2_hw(float x) { return __builtin_amdgcn_exp2f(x); }
#else
__device__ __forceinline__ float exp2_hw(float x) { return exp2f(x); }
#endif

// packed f32x2 -> bf16x2 (RNE), single VOP3
__device__ __forceinline__ u32 cvt_pk_bf16(float a, float b) {
  u32 r;
  asm("v_cvt_pk_bf16_f32 %0, %1, %2" : "=v"(r) : "v"(a), "v"(b));
  return r;
}

__device__ __forceinline__ void gload16(const u16* g, u16* l) {
  __builtin_amdgcn_global_load_lds(
      (const __attribute__((address_space(1))) u32*)g,
      (__attribute__((address_space(3))) u32*)l, 16, 0, 0);
}

// ------- transpose + convert body: src[K][N] f32 -> dst[N][K] bf16 ----------
__device__ __forceinline__ void transpose_body(const float* __restrict__ src,
                                               u16* __restrict__ dst,
                                               int N, int K, int nt, int kt,
                                               int t) {
  __shared__ float T[64][65];
#pragma unroll
  for (int it = 0; it < 4; ++it) {
    int r = it * 16 + (t >> 4), c = (t & 15) * 4;
    float4 v = *(const float4*)(src + (size_t)(kt + r) * N + nt + c);
    T[r][c] = v.x; T[r][c + 1] = v.y; T[r][c + 2] = v.z; T[r][c + 3] = v.w;
  }
  __syncthreads();
#pragma unroll
  for (int it = 0; it < 2; ++it) {
    int n = it * 32 + (t >> 3), k8 = (t & 7) * 8;
    ushort4 w0, w1;
    w0.x = f2bf(T[k8 + 0][n]); w0.y = f2bf(T[k8 + 1][n]);
    w0.z = f2bf(T[k8 + 2][n]); w0.w = f2bf(T[k8 + 3][n]);
    w1.x = f2bf(T[k8 + 4][n]); w1.y = f2bf(T[k8 + 5][n]);
    w1.z = f2bf(T[k8 + 6][n]); w1.w = f2bf(T[k8 + 7][n]);
    *(ushort4*)(dst + (size_t)(nt + n) * K + kt + k8) = w0;
    *(ushort4*)(dst + (size_t)(nt + n) * K + kt + k8 + 4) = w1;
  }
}

__device__ __forceinline__ void cvt_body(const float* __restrict__ hidden,
                                         u16* __restrict__ Hb, int bx, int t) {
  int i = (bx * 256 + t) * 8;
  float4 v0 = *(const float4*)(hidden + i);
  float4 v1 = *(const float4*)(hidden + i + 4);
  ushort4 w0, w1;
  w0.x = f2bf(v0.x); w0.y = f2bf(v0.y); w0.z = f2bf(v0.z); w0.w = f2bf(v0.w);
  w1.x = f2bf(v1.x); w1.y = f2bf(v1.y); w1.z = f2bf(v1.z); w1.w = f2bf(v1.w);
  *(ushort4*)(Hb + i) = w0;
  *(ushort4*)(Hb + i + 4) = w1;
}

__device__ __forceinline__ void wqkv_t_body(const float* __restrict__ Wq,
                                            const float* __restrict__ Wk,
                                            const float* __restrict__ Wv,
                                            u16* __restrict__ WT, int id, int t) {
  const int x = id % 48, y = id / 48;
  const float* src; u16* dst; int N, nt;
  if (x < 32)      { src = Wq; dst = WT;                    N = 2048; nt = x * 64; }
  else if (x < 40) { src = Wk; dst = WT + 2048ull * 2048;   N = 512;  nt = (x - 32) * 64; }
  else             { src = Wv; dst = WT + 2560ull * 2048;   N = 512;  nt = (x - 40) * 64; }
  transpose_body(src, dst, N, 2048, nt, y * 64, t);
}

// ------- merged preprocessing (small-ws path): cvt + Wqkv transpose ---------
__global__ __launch_bounds__(256) void k_pre(const float* __restrict__ hidden,
                                             u16* __restrict__ Hb,
                                             const float* __restrict__ Wq,
                                             const float* __restrict__ Wk,
                                             const float* __restrict__ Wv,
                                             u16* __restrict__ WT) {
  const int bx = blockIdx.x, t = threadIdx.x;
  if (bx < 2048) { cvt_body(hidden, Hb, bx, t); return; }
  wqkv_t_body(Wq, Wk, Wv, WT, bx - 2048, t);
}

// ------- merged preprocessing (big-ws path): + Wo transpose -----------------
// WoT has a dedicated region -> its transpose runs here, overlapped with the
// cvt/WT work, instead of as a serial launch between QKV GEMM and flash.
__global__ __launch_bounds__(256) void k_pre_all(const float* __restrict__ hidden,
                                                 u16* __restrict__ Hb,
                                                 const float* __restrict__ Wq,
                                                 const float* __restrict__ Wk,
                                                 const float* __restrict__ Wv,
                                                 u16* __restrict__ WT,
                                                 const float* __restrict__ Wo,
                                                 u16* __restrict__ WoT) {
  const int bx = blockIdx.x, t = threadIdx.x;
  if (bx < 2048) { cvt_body(hidden, Hb, bx, t); return; }
  if (bx < 3584) { wqkv_t_body(Wq, Wk, Wv, WT, bx - 2048, t); return; }
  const int id = bx - 3584;  // 0..1023
  transpose_body(Wo, WoT, 2048, 2048, (id & 31) * 64, (id >> 5) * 64, t);
}

__global__ __launch_bounds__(256) void k_transpose(const float* __restrict__ src,
                                                   u16* __restrict__ dst,
                                                   int N, int K) {
  transpose_body(src, dst, N, K, blockIdx.x * 64, blockIdx.y * 64, threadIdx.x);
}

// ------- QKV GEMM with FUSED epilogue: norm+RoPE (Q/K) or Vt write (V) ------
// (R12-proven) BN=128 spans exactly one head; RMSNorm+RoPE on f32
// accumulators; V blocks write Vt directly. Main loop = reads-first BK=64
// XOR-swizzle structure.
__global__ __launch_bounds__(256) void k_gemm_qkv(const u16* __restrict__ A,
                                                  const u16* __restrict__ BT,
                                                  u16* __restrict__ QKV,
                                                  u16* __restrict__ Vt,
                                                  const float* __restrict__ qsc,
                                                  const float* __restrict__ ksc,
                                                  const float* __restrict__ cosp,
                                                  const float* __restrict__ sinp) {
  __shared__ __align__(16) char smem[49152];
  u16* AsB = (u16*)smem;            // [2][64*64]
  u16* BsB = (u16*)(smem + 16384);  // [2][128*64]
  const int K = 2048;
  const int t = threadIdx.x, w = t >> 6, lane = t & 63;
  const int l15 = lane & 15, quad = lane >> 4;
  const int m0 = blockIdx.y * 64, n0 = blockIdx.x * 128;

  const int srow = lane >> 3;                       // 0..7 within issue
  const int schunk = (lane & 7) ^ srow;             // pre-swizzled source chunk
  const u16* Agb = A + (size_t)(m0 + w * 8 + srow) * K + schunk * 8;
  const u16* Bgb = BT + (size_t)(n0 + w * 8 + srow) * K + schunk * 8;

  f32x4 acc[4][2];
#pragma unroll
  for (int i = 0; i < 4; ++i)
#pragma unroll
    for (int j = 0; j < 2; ++j) acc[i][j] = (f32x4){0.f, 0.f, 0.f, 0.f};

  auto STAGE = [&](int k0, int b) {
#pragma unroll
    for (int it = 0; it < 2; ++it)
      gload16(Agb + (size_t)it * 32 * K + k0, AsB + b * 4096 + (w * 8 + it * 32) * 64);
#pragma unroll
    for (int it = 0; it < 4; ++it)
      gload16(Bgb + (size_t)it * 32 * K + k0, BsB + b * 8192 + (w * 8 + it * 32) * 64);
  };

  STAGE(0, 0);
  __syncthreads();  // buf0 ready
  int cur = 0;
  for (int k0 = 0; k0 < K; k0 += 64) {
    short8 af[4][2], bf[2][2];
#pragma unroll
    for (int k2 = 0; k2 < 2; ++k2) {
      int ch = (k2 * 4 + quad) ^ (l15 & 7);
#pragma unroll
      for (int i = 0; i < 4; ++i)
        af[i][k2] = *(const short8*)&AsB[cur * 4096 + (i * 16 + l15) * 64 + ch * 8];
#pragma unroll
      for (int j = 0; j < 2; ++j)
        bf[j][k2] = *(const short8*)&BsB[cur * 8192 + (w * 32 + j * 16 + l15) * 64 + ch * 8];
    }

    if (k0 + 64 < K) STAGE(k0 + 64, cur ^ 1);  // DMA flies under the MFMAs

#pragma unroll
    for (int k2 = 0; k2 < 2; ++k2)
#pragma unroll
      for (int i = 0; i < 4; ++i)
#pragma unroll
        for (int j = 0; j < 2; ++j)
          acc[i][j] = __builtin_amdgcn_mfma_f32_16x16x32_bf16(af[i][k2], bf[j][k2], acc[i][j], 0, 0, 0);

    __syncthreads();  // drains prefetch + all waves done reading cur
    cur ^= 1;
  }

  // ---------------- fused epilogue ----------------
  const int colL0 = w * 32 + l15;        // j=0 local col
  const int colL1 = w * 32 + 16 + l15;   // j=1 local col

  if (n0 < 2560) {  // Q or K head: RMSNorm + RoPE on f32 accumulators
    const float* sc = (n0 < 2048) ? qsc : ksc;
    const float scale = (n0 < 2048) ? QSCALE : 1.0f;

    float ssp[4][4];
#pragma unroll
    for (int i = 0; i < 4; ++i)
#pragma unroll
      for (int r = 0; r < 4; ++r)
        ssp[i][r] = acc[i][0][r] * acc[i][0][r] + acc[i][1][r] * acc[i][1][r];
#pragma unroll
    for (int o = 1; o < 16; o <<= 1)
#pragma unroll
      for (int i = 0; i < 4; ++i)
#pragma unroll
        for (int r = 0; r < 4; ++r) ssp[i][r] += __shfl_xor(ssp[i][r], o, 64);
    float* red = (float*)smem;           // 256 f32
    float* X = (float*)(smem + 2048);    // [64][132] f32
    if (l15 == 0) {
#pragma unroll
      for (int i = 0; i < 4; ++i)
#pragma unroll
        for (int r = 0; r < 4; ++r) red[w * 64 + i * 16 + quad * 4 + r] = ssp[i][r];
    }
    __syncthreads();
    float rinv[4][4];
#pragma unroll
    for (int i = 0; i < 4; ++i)
#pragma unroll
      for (int r = 0; r < 4; ++r) {
        int row = i * 16 + quad * 4 + r;
        float s = red[row] + red[64 + row] + red[128 + row] + red[192 + row];
        rinv[i][r] = rsqrtf(s * (1.0f / 128.0f) + 1e-6f) * scale;
      }
    float sc0 = sc[colL0], sc1 = sc[colL1];
#pragma unroll
    for (int i = 0; i < 4; ++i)
#pragma unroll
      for (int r = 0; r < 4; ++r) {
        int row = i * 16 + quad * 4 + r;
        X[row * 132 + colL0] = acc[i][0][r] * rinv[i][r] * sc0;
        X[row * 132 + colL1] = acc[i][1][r] * rinv[i][r] * sc1;
      }
    __syncthreads();
    float sgn0 = (colL0 < 64) ? -1.f : 1.f;
    float sgn1 = (colL1 < 64) ? -1.f : 1.f;
#pragma unroll
    for (int i = 0; i < 4; ++i)
#pragma unroll
      for (int r = 0; r < 4; ++r) {
        int row = i * 16 + quad * 4 + r;
        int srw = m0 + row;
        float xn0 = X[row * 132 + colL0], p0 = X[row * 132 + (colL0 ^ 64)];
        float xn1 = X[row * 132 + colL1], p1 = X[row * 132 + (colL1 ^ 64)];
        float v0 = xn0 * cosp[srw * D + colL0] + sgn0 * p0 * sinp[srw * D + colL0];
        float v1 = xn1 * cosp[srw * D + colL1] + sgn1 * p1 * sinp[srw * D + colL1];
        QKV[(size_t)srw * QKVP + n0 + colL0] = f2bf(v0);
        QKV[(size_t)srw * QKVP + n0 + colL1] = f2bf(v1);
      }
  } else {  // V head: write transposed Vt[gd][s] directly
#pragma unroll
    for (int i = 0; i < 4; ++i) {
      int sbase = m0 + i * 16 + quad * 4;
      ushort4 w0, w1;
      w0.x = f2bf(acc[i][0][0]); w0.y = f2bf(acc[i][0][1]);
      w0.z = f2bf(acc[i][0][2]); w0.w = f2bf(acc[i][0][3]);
      w1.x = f2bf(acc[i][1][0]); w1.y = f2bf(acc[i][1][1]);
      w1.z = f2bf(acc[i][1][2]); w1.w = f2bf(acc[i][1][3]);
      *(ushort4*)(Vt + (size_t)(n0 - 2560 + colL0) * S + sbase) = w0;
      *(ushort4*)(Vt + (size_t)(n0 - 2560 + colL1) * S + sbase) = w1;
    }
  }
}

// ------- MFMA GEMM (Wo): BM=64 x BN=128, BK=64, reads-first, XOR swizzle ----
__global__ __launch_bounds__(256) void k_gemm_mfma(const u16* __restrict__ A,
                                                   const u16* __restrict__ BT,
                                                   void* __restrict__ Cout,
                                                   int N, int K, int out_bf16) {
  __shared__ __align__(16) u16 As[2][64 * 64];
  __shared__ __align__(16) u16 Bs[2][128 * 64];
  const int t = threadIdx.x, w = t >> 6, lane = t & 63;
  const int l15 = lane & 15, quad = lane >> 4;
  const int m0 = blockIdx.y * 64, n0 = blockIdx.x * 128;

  const int srow = lane >> 3;                       // 0..7 within issue
  const int schunk = (lane & 7) ^ srow;             // pre-swizzled source chunk
  const u16* Agb = A + (size_t)(m0 + w * 8 + srow) * K + schunk * 8;
  const u16* Bgb = BT + (size_t)(n0 + w * 8 + srow) * K + schunk * 8;

  f32x4 acc[4][2];
#pragma unroll
  for (int i = 0; i < 4; ++i)
#pragma unroll
    for (int j = 0; j < 2; ++j) acc[i][j] = (f32x4){0.f, 0.f, 0.f, 0.f};

  auto STAGE = [&](int k0, int b) {
#pragma unroll
    for (int it = 0; it < 2; ++it)
      gload16(Agb + (size_t)it * 32 * K + k0, &As[b][(w * 8 + it * 32) * 64]);
#pragma unroll
    for (int it = 0; it < 4; ++it)
      gload16(Bgb + (size_t)it * 32 * K + k0, &Bs[b][(w * 8 + it * 32) * 64]);
  };

  STAGE(0, 0);
  __syncthreads();  // buf0 ready
  int cur = 0;
  for (int k0 = 0; k0 < K; k0 += 64) {
    short8 af[4][2], bf[2][2];
#pragma unroll
    for (int k2 = 0; k2 < 2; ++k2) {
      int ch = (k2 * 4 + quad) ^ (l15 & 7);
#pragma unroll
      for (int i = 0; i < 4; ++i)
        af[i][k2] = *(const short8*)&As[cur][(i * 16 + l15) * 64 + ch * 8];
#pragma unroll
      for (int j = 0; j < 2; ++j)
        bf[j][k2] = *(const short8*)&Bs[cur][(w * 32 + j * 16 + l15) * 64 + ch * 8];
    }

    if (k0 + 64 < K) STAGE(k0 + 64, cur ^ 1);  // DMA flies under the MFMAs

#pragma unroll
    for (int k2 = 0; k2 < 2; ++k2)
#pragma unroll
      for (int i = 0; i < 4; ++i)
#pragma unroll
        for (int j = 0; j < 2; ++j)
          acc[i][j] = __builtin_amdgcn_mfma_f32_16x16x32_bf16(af[i][k2], bf[j][k2], acc[i][j], 0, 0, 0);

    __syncthreads();  // drains prefetch + all waves done reading cur
    cur ^= 1;
  }

  if (out_bf16) {
    u16* C = (u16*)Cout;
#pragma unroll
    for (int i = 0; i < 4; ++i)
#pragma unroll
      for (int j = 0; j < 2; ++j) {
        int col = n0 + w * 32 + j * 16 + l15;
#pragma unroll
        for (int r = 0; r < 4; ++r)
          C[(size_t)(m0 + i * 16 + quad * 4 + r) * N + col] = f2bf(acc[i][j][r]);
      }
  } else {
    float* C = (float*)Cout;
#pragma unroll
    for (int i = 0; i < 4; ++i)
#pragma unroll
      for (int j = 0; j < 2; ++j) {
        int col = n0 + w * 32 + j * 16 + l15;
#pragma unroll
        for (int r = 0; r < 4; ++r)
          C[(size_t)(m0 + i * 16 + quad * 4 + r) * N + col] = acc[i][j][r];
      }
  }
}

// ---------------- flash attention (R10-frozen) ------------------------------
#define KP 128   // K LDS row pitch (u16), unpadded (DMA requirement)
#define PTP 72   // P pitch (u16): b64-write / b128-read aligned

__global__ __launch_bounds__(256) void k_flash(const u16* __restrict__ QKV,
                                               const u16* __restrict__ Vt,
                                               u16* __restrict__ O) {
  const int h = blockIdx.y, g = h >> 2;
  const int qt = (h < 8) ? (31 - (int)blockIdx.x) : (int)blockIdx.x;
  const int t = threadIdx.x;
  const int w = t >> 6, lane = t & 63, l15 = lane & 15, quad = lane >> 4;

  __shared__ __align__(16) u16 Klds[2][64 * KP];
  __shared__ __align__(16) u16 Vlds[128 * 64];     // [d][key], XOR-swizzled
  __shared__ __align__(16) u16 Pt[4][16 * PTP];    // [qcol][key] per wave

  const int qbase = qt * 64 + w * 16;
  const int qrow = qbase + l15;

  short8 qf[4];
  {
    const u16* qp = QKV + (size_t)qrow * QKVP + h * D + quad * 8;
#pragma unroll
    for (int c = 0; c < 4; ++c) qf[c] = *(const short8*)(qp + c * 32);
  }

  float m = NEG_INF, l = 0.f;
  f32x4 oacc[8];
#pragma unroll
  for (int nc = 0; nc < 8; ++nc) oacc[nc] = (f32x4){0.f, 0.f, 0.f, 0.f};

  const int nt = qt + 1;
  const int dd = t >> 3, cc = t & 7;  // V staging coords

  auto KLOAD = [&](int j0, int b) {  // DMA 4 rows per wave per issue
#pragma unroll
    for (int it = 0; it < 4; ++it) {
      int rl = w * 16 + it * 4 + quad;                 // tile-local key row
      int gchunk = (lane & 15) ^ (rl & 7);             // source swizzle
      const u16* gp = QKV + (size_t)(j0 + rl) * QKVP + 2048 + g * D + gchunk * 8;
      gload16(gp, &Klds[b][(w * 16 + it * 4) * KP]);
    }
  };
  auto VLOAD = [&](int j0, uint4* vr) {
#pragma unroll
    for (int it = 0; it < 4; ++it)
      vr[it] = *(const uint4*)(Vt + (size_t)(g * D + dd + it * 32) * S + j0 + cc * 8);
  };
  auto VWRITE = [&](uint4* vr) {
#pragma unroll
    for (int it = 0; it < 4; ++it) {
      int d = dd + it * 32;
      *(uint4*)&Vlds[d * 64 + ((cc ^ (d & 7)) * 8)] = vr[it];
    }
  };
  auto QKT = [&](int b, f32x4* sa) {
#pragma unroll
    for (int sub = 0; sub < 4; ++sub) {
      f32x4 acc = {0.f, 0.f, 0.f, 0.f};
#pragma unroll
      for (int c = 0; c < 4; ++c) {
        int ch = (c * 4 + quad) ^ (l15 & 7);  // undo source swizzle
        short8 kf = *(const short8*)&Klds[b][(sub * 16 + l15) * KP + ch * 8];
        acc = __builtin_amdgcn_mfma_f32_16x16x32_bf16(kf, qf[c], acc, 0, 0, 0);
      }
      sa[sub] = acc;
    }
  };
  auto SMPV = [&](int jt, f32x4* sa) {
    const int j0 = jt * 64;
    if (jt == nt - 1) {  // causal mask, diagonal tile only
#pragma unroll
      for (int sub = 0; sub < 4; ++sub) {
        int keyb = j0 + sub * 16 + quad * 4;
#pragma unroll
        for (int r = 0; r < 4; ++r)
          if (keyb + r > qrow) sa[sub][r] = NEG_INF;
      }
    }
    float tmax = sa[0][0];
#pragma unroll
    for (int sub = 0; sub < 4; ++sub)
#pragma unroll
      for (int r = 0; r < 4; ++r) tmax = fmaxf(tmax, sa[sub][r]);
    tmax = fmaxf(tmax, __shfl_xor(tmax, 16, 64));
    tmax = fmaxf(tmax, __shfl_xor(tmax, 32, 64));
    float mn = fmaxf(m, tmax);
    float alpha = exp2_hw(m - mn);
    m = mn;
    float rs = 0.f;
#pragma unroll
    for (int sub = 0; sub < 4; ++sub) {
      float p0 = exp2_hw(sa[sub][0] - m);
      float p1 = exp2_hw(sa[sub][1] - m);
      float p2 = exp2_hw(sa[sub][2] - m);
      float p3 = exp2_hw(sa[sub][3] - m);
      rs += (p0 + p1) + (p2 + p3);
      u32 lo = cvt_pk_bf16(p0, p1);
      u32 hi = cvt_pk_bf16(p2, p3);
      *(uint2*)&Pt[w][l15 * PTP + sub * 16 + quad * 4] = make_uint2(lo, hi);
    }
    rs += __shfl_xor(rs, 16, 64);
    rs += __shfl_xor(rs, 32, 64);
    l = l * alpha + rs;
#pragma unroll
    for (int nc = 0; nc < 8; ++nc) {
      oacc[nc][0] *= alpha; oacc[nc][1] *= alpha;
      oacc[nc][2] *= alpha; oacc[nc][3] *= alpha;
    }
#pragma unroll
    for (int kc = 0; kc < 2; ++kc) {
      short8 pf = *(const short8*)&Pt[w][l15 * PTP + kc * 32 + quad * 8];
#pragma unroll
      for (int nc = 0; nc < 8; ++nc) {
        int d = nc * 16 + l15;
        short8 vf = *(const short8*)&Vlds[d * 64 + (((kc * 4 + quad) ^ (d & 7)) * 8)];
        oacc[nc] = __builtin_amdgcn_mfma_f32_16x16x32_bf16(vf, pf, oacc[nc], 0, 0, 0);
      }
    }
  };

  uint4 vrA[4], vrB[4];
  f32x4 sa[4];
  KLOAD(0, 0);
  VLOAD(0, vrA);
  for (int jt = 0; jt < nt; jt += 2) {
    __syncthreads();                       // drains K(jt) DMA + all VMEM
    VWRITE(vrA);
    __syncthreads();                       // V(jt) visible
    QKT(0, sa);                            // no outstanding VMEM -> no stall
    if (jt + 1 < nt) { KLOAD((jt + 1) * 64, 1); VLOAD((jt + 1) * 64, vrB); }
    SMPV(jt, sa);                          // covers prefetch latency
    if (jt + 1 < nt) {
      __syncthreads();                     // drains K(jt+1)+V(jt+1), covered
      VWRITE(vrB);
      __syncthreads();
      QKT(1, sa);
      if (jt + 2 < nt) { KLOAD((jt + 2) * 64, 0); VLOAD((jt + 2) * 64, vrA); }
      SMPV(jt + 1, sa);
    }
  }

  // ---- epilogue: O[q][d] = O^T / l ----
  float inv = 1.0f / l;
  u16* orow = O + (size_t)qrow * HID + h * D;
#pragma unroll
  for (int nc = 0; nc < 8; ++nc) {
    ushort4 wv;
    wv.x = f2bf(oacc[nc][0] * inv); wv.y = f2bf(oacc[nc][1] * inv);
    wv.z = f2bf(oacc[nc][2] * inv); wv.w = f2bf(oacc[nc][3] * inv);
    *(ushort4*)(orow + nc * 16 + quad * 4) = wv;
  }
}

// ---------------- final RMSNorm over HIDDEN=2048 (bf16 input) ---------------
__device__ __forceinline__ float blockSum256(float v, float* red, int t) {
#pragma unroll
  for (int o = 32; o; o >>= 1) v += __shfl_xor(v, o, 64);
  if ((t & 63) == 0) red[t >> 6] = v;
  __syncthreads();
  v = red[0] + red[1] + red[2] + red[3];
  __syncthreads();
  return v;
}

__global__ __launch_bounds__(256) void k_fnorm(const u16* __restrict__ X,
                                               const float* __restrict__ sc,
                                               float* __restrict__ out) {
  const int s = blockIdx.x, t = threadIdx.x;
  const u16* row = X + (size_t)s * HID + t * 8;
  short8 rv = *(const short8*)row;
  float x[8];
#pragma unroll
  for (int ii = 0; ii < 8; ++ii) x[ii] = bf2f((u16)rv[ii]);
  float ss = 0.f;
#pragma unroll
  for (int ii = 0; ii < 8; ++ii) ss += x[ii] * x[ii];
  __shared__ float red[4];
  float tot = blockSum256(ss, red, t);
  float rinv = rsqrtf(tot * (1.0f / 2048.0f) + 1e-6f);
  float4 s0 = *(const float4*)(sc + t * 8);
  float4 s1 = *(const float4*)(sc + t * 8 + 4);
  float4 w0 = make_float4(x[0] * rinv * s0.x, x[1] * rinv * s0.y,
                          x[2] * rinv * s0.z, x[3] * rinv * s0.w);
  float4 w1 = make_float4(x[4] * rinv * s1.x, x[5] * rinv * s1.y,
                          x[6] * rinv * s1.z, x[7] * rinv * s1.w);
  *(float4*)(out + (size_t)s * HID + t * 8) = w0;
  *(float4*)(out + (size_t)s * HID + t * 8 + 4) = w1;
}

extern "C" void kernel_launch(void* const* d_in, const int* in_sizes, int n_in,
                              void* d_out, int out_size, void* d_ws, size_t ws_size,
                              hipStream_t stream) {
  const float* hidden = (const float*)d_in[0];
  const float* cosp   = (const float*)d_in[1];
  const float* sinp   = (const float*)d_in[2];
  const float* Wq     = (const float*)d_in[3];
  const float* Wk     = (const float*)d_in[4];
  const float* Wv     = (const float*)d_in[5];
  const float* Wo     = (const float*)d_in[6];
  const float* qsc    = (const float*)d_in[7];
  const float* ksc    = (const float*)d_in[8];
  const float* lsc    = (const float*)d_in[9];
  float* out = (float*)d_out;

  char* ws = (char*)d_ws;
  u16*   Hb  = (u16*)(ws);                   // [S][HID] bf16, 8 MiB
  u16*   WT  = (u16*)(ws + (8ull << 20));    // [3072][2048] bf16, 12 MiB
  u16*   An  = (u16*)(ws + (8ull << 20));    // overlays WT (after QKV GEMM)
  u16*   QKV = (u16*)(ws + (20ull << 20));   // [S][3072] bf16, 12 MiB
  u16*   Ob  = (u16*)(ws + (20ull << 20));   // bf16 [S][HID], 8 MiB (overlays QKV)
  u16*   Vtb = (u16*)(ws + (32ull << 20));   // [512][2048] bf16, 2 MiB

  const bool bigws = ws_size >= (43ull << 20);
  // big-ws: WoT gets a dedicated region -> transpose folds into k_pre_all
  // (overlapped), no serial k_transpose launch. small-ws: WoT overlays Hb.
  u16* WoT = bigws ? (u16*)(ws + (34ull << 20)) : (u16*)ws;

  if (bigws) {
    k_pre_all<<<2048 + 1536 + 1024, 256, 0, stream>>>(hidden, Hb, Wq, Wk, Wv, WT, Wo, WoT);
  } else {
    k_pre<<<2048 + 1536, 256, 0, stream>>>(hidden, Hb, Wq, Wk, Wv, WT);
  }
  k_gemm_qkv<<<dim3(24, 32), 256, 0, stream>>>(Hb, WT, QKV, Vtb, qsc, ksc, cosp, sinp);
  if (!bigws) {
    k_transpose<<<dim3(32, 32), 256, 0, stream>>>(Wo, WoT, 2048, 2048);  // Hb dead
  }
  k_flash<<<dim3(32, NH), 256, 0, stream>>>(QKV, Vtb, An);
  k_gemm_mfma<<<dim3(16, 32), 256, 0, stream>>>(An, WoT, Ob, 2048, 2048, 1);
  k_fnorm<<<S, 256, 0, stream>>>(Ob, lsc, out);
}

// Round 15
// 271.181 us; speedup vs baseline: 1.0590x; 1.0439x over previous
//
#include <hip/hip_runtime.h>

typedef unsigned short u16;
typedef unsigned int u32;

#define S 2048
#define HID 2048
#define NH 16
#define NKV 4
#define D 128
#define QKVP 3072  // QKV buffer pitch (Q|K|V concat per row)
// 1/sqrt(128) * log2(e): scores come out of QK^T already in log2 domain
#define QSCALE (0.08838834764831845f * 1.4426950408889634f)
#define NEG_INF -3.0e38f

typedef __attribute__((ext_vector_type(8))) short short8;  // 8 bf16 = 4 VGPRs
typedef __attribute__((ext_vector_type(4))) float f32x4;

__device__ __forceinline__ float bf2f(u16 u) {
  union { u32 i; float f; } c; c.i = ((u32)u) << 16; return c.f;
}
__device__ __forceinline__ u16 f2bf(float f) {
  union { float f; u32 i; } c; c.f = f;
  u32 x = c.i;
  u32 r = x + 0x7fffu + ((x >> 16) & 1u);  // RNE
  return (u16)(r >> 16);
}

#if __has_builtin(__builtin_amdgcn_exp2f)
__device__ __forceinline__ float exp2_hw(float x) { return __builtin_amdgcn_exp2f(x); }
#else
__device__ __forceinline__ float exp2_hw(float x) { return exp2f(x); }
#endif

// packed f32x2 -> bf16x2 (RNE), single VOP3
__device__ __forceinline__ u32 cvt_pk_bf16(float a, float b) {
  u32 r;
  asm("v_cvt_pk_bf16_f32 %0, %1, %2" : "=v"(r) : "v"(a), "v"(b));
  return r;
}

__device__ __forceinline__ void gload16(const u16* g, u16* l) {
  __builtin_amdgcn_global_load_lds(
      (const __attribute__((address_space(1))) u32*)g,
      (__attribute__((address_space(3))) u32*)l, 16, 0, 0);
}

// ------- transpose + convert body: src[K][N] f32 -> dst[N][K] bf16 ----------
__device__ __forceinline__ void transpose_body(const float* __restrict__ src,
                                               u16* __restrict__ dst,
                                               int N, int K, int nt, int kt,
                                               int t) {
  __shared__ float T[64][65];
#pragma unroll
  for (int it = 0; it < 4; ++it) {
    int r = it * 16 + (t >> 4), c = (t & 15) * 4;
    float4 v = *(const float4*)(src + (size_t)(kt + r) * N + nt + c);
    T[r][c] = v.x; T[r][c + 1] = v.y; T[r][c + 2] = v.z; T[r][c + 3] = v.w;
  }
  __syncthreads();
#pragma unroll
  for (int it = 0; it < 2; ++it) {
    int n = it * 32 + (t >> 3), k8 = (t & 7) * 8;
    ushort4 w0, w1;
    w0.x = f2bf(T[k8 + 0][n]); w0.y = f2bf(T[k8 + 1][n]);
    w0.z = f2bf(T[k8 + 2][n]); w0.w = f2bf(T[k8 + 3][n]);
    w1.x = f2bf(T[k8 + 4][n]); w1.y = f2bf(T[k8 + 5][n]);
    w1.z = f2bf(T[k8 + 6][n]); w1.w = f2bf(T[k8 + 7][n]);
    *(ushort4*)(dst + (size_t)(nt + n) * K + kt + k8) = w0;
    *(ushort4*)(dst + (size_t)(nt + n) * K + kt + k8 + 4) = w1;
  }
}

__device__ __forceinline__ void cvt_body(const float* __restrict__ hidden,
                                         u16* __restrict__ Hb, int bx, int t) {
  int i = (bx * 256 + t) * 8;
  float4 v0 = *(const float4*)(hidden + i);
  float4 v1 = *(const float4*)(hidden + i + 4);
  ushort4 w0, w1;
  w0.x = f2bf(v0.x); w0.y = f2bf(v0.y); w0.z = f2bf(v0.z); w0.w = f2bf(v0.w);
  w1.x = f2bf(v1.x); w1.y = f2bf(v1.y); w1.z = f2bf(v1.z); w1.w = f2bf(v1.w);
  *(ushort4*)(Hb + i) = w0;
  *(ushort4*)(Hb + i + 4) = w1;
}

__device__ __forceinline__ void wqkv_t_body(const float* __restrict__ Wq,
                                            const float* __restrict__ Wk,
                                            const float* __restrict__ Wv,
                                            u16* __restrict__ WT, int id, int t) {
  const int x = id % 48, y = id / 48;
  const float* src; u16* dst; int N, nt;
  if (x < 32)      { src = Wq; dst = WT;                    N = 2048; nt = x * 64; }
  else if (x < 40) { src = Wk; dst = WT + 2048ull * 2048;   N = 512;  nt = (x - 32) * 64; }
  else             { src = Wv; dst = WT + 2560ull * 2048;   N = 512;  nt = (x - 40) * 64; }
  transpose_body(src, dst, N, 2048, nt, y * 64, t);
}

// ------- merged preprocessing (small-ws path): cvt + Wqkv transpose ---------
__global__ __launch_bounds__(256) void k_pre(const float* __restrict__ hidden,
                                             u16* __restrict__ Hb,
                                             const float* __restrict__ Wq,
                                             const float* __restrict__ Wk,
                                             const float* __restrict__ Wv,
                                             u16* __restrict__ WT) {
  const int bx = blockIdx.x, t = threadIdx.x;
  if (bx < 2048) { cvt_body(hidden, Hb, bx, t); return; }
  wqkv_t_body(Wq, Wk, Wv, WT, bx - 2048, t);
}

// ------- merged preprocessing (big-ws path): + Wo transpose -----------------
// WoT has a dedicated region -> its transpose runs here, overlapped with the
// cvt/WT work, instead of as a serial launch between QKV GEMM and flash.
__global__ __launch_bounds__(256) void k_pre_all(const float* __restrict__ hidden,
                                                 u16* __restrict__ Hb,
                                                 const float* __restrict__ Wq,
                                                 const float* __restrict__ Wk,
                                                 const float* __restrict__ Wv,
                                                 u16* __restrict__ WT,
                                                 const float* __restrict__ Wo,
                                                 u16* __restrict__ WoT) {
  const int bx = blockIdx.x, t = threadIdx.x;
  if (bx < 2048) { cvt_body(hidden, Hb, bx, t); return; }
  if (bx < 3584) { wqkv_t_body(Wq, Wk, Wv, WT, bx - 2048, t); return; }
  const int id = bx - 3584;  // 0..1023
  transpose_body(Wo, WoT, 2048, 2048, (id & 31) * 64, (id >> 5) * 64, t);
}

__global__ __launch_bounds__(256) void k_transpose(const float* __restrict__ src,
                                                   u16* __restrict__ dst,
                                                   int N, int K) {
  transpose_body(src, dst, N, K, blockIdx.x * 64, blockIdx.y * 64, threadIdx.x);
}

// ------- QKV GEMM with FUSED epilogue: norm+RoPE (Q/K) or Vt write (V) ------
// (proven) BN=128 spans exactly one head; RMSNorm+RoPE on f32 accumulators;
// V blocks write Vt directly. Main loop = reads-first BK=64 XOR-swizzle.
__global__ __launch_bounds__(256) void k_gemm_qkv(const u16* __restrict__ A,
                                                  const u16* __restrict__ BT,
                                                  u16* __restrict__ QKV,
                                                  u16* __restrict__ Vt,
                                                  const float* __restrict__ qsc,
                                                  const float* __restrict__ ksc,
                                                  const float* __restrict__ cosp,
                                                  const float* __restrict__ sinp) {
  __shared__ __align__(16) char smem[49152];
  u16* AsB = (u16*)smem;            // [2][64*64]
  u16* BsB = (u16*)(smem + 16384);  // [2][128*64]
  const int K = 2048;
  const int t = threadIdx.x, w = t >> 6, lane = t & 63;
  const int l15 = lane & 15, quad = lane >> 4;
  const int m0 = blockIdx.y * 64, n0 = blockIdx.x * 128;

  const int srow = lane >> 3;                       // 0..7 within issue
  const int schunk = (lane & 7) ^ srow;             // pre-swizzled source chunk
  const u16* Agb = A + (size_t)(m0 + w * 8 + srow) * K + schunk * 8;
  const u16* Bgb = BT + (size_t)(n0 + w * 8 + srow) * K + schunk * 8;

  f32x4 acc[4][2];
#pragma unroll
  for (int i = 0; i < 4; ++i)
#pragma unroll
    for (int j = 0; j < 2; ++j) acc[i][j] = (f32x4){0.f, 0.f, 0.f, 0.f};

  auto STAGE = [&](int k0, int b) {
#pragma unroll
    for (int it = 0; it < 2; ++it)
      gload16(Agb + (size_t)it * 32 * K + k0, AsB + b * 4096 + (w * 8 + it * 32) * 64);
#pragma unroll
    for (int it = 0; it < 4; ++it)
      gload16(Bgb + (size_t)it * 32 * K + k0, BsB + b * 8192 + (w * 8 + it * 32) * 64);
  };

  STAGE(0, 0);
  __syncthreads();  // buf0 ready
  int cur = 0;
  for (int k0 = 0; k0 < K; k0 += 64) {
    short8 af[4][2], bf[2][2];
#pragma unroll
    for (int k2 = 0; k2 < 2; ++k2) {
      int ch = (k2 * 4 + quad) ^ (l15 & 7);
#pragma unroll
      for (int i = 0; i < 4; ++i)
        af[i][k2] = *(const short8*)&AsB[cur * 4096 + (i * 16 + l15) * 64 + ch * 8];
#pragma unroll
      for (int j = 0; j < 2; ++j)
        bf[j][k2] = *(const short8*)&BsB[cur * 8192 + (w * 32 + j * 16 + l15) * 64 + ch * 8];
    }

    if (k0 + 64 < K) STAGE(k0 + 64, cur ^ 1);  // DMA flies under the MFMAs

#pragma unroll
    for (int k2 = 0; k2 < 2; ++k2)
#pragma unroll
      for (int i = 0; i < 4; ++i)
#pragma unroll
        for (int j = 0; j < 2; ++j)
          acc[i][j] = __builtin_amdgcn_mfma_f32_16x16x32_bf16(af[i][k2], bf[j][k2], acc[i][j], 0, 0, 0);

    __syncthreads();  // drains prefetch + all waves done reading cur
    cur ^= 1;
  }

  // ---------------- fused epilogue ----------------
  const int colL0 = w * 32 + l15;        // j=0 local col
  const int colL1 = w * 32 + 16 + l15;   // j=1 local col

  if (n0 < 2560) {  // Q or K head: RMSNorm + RoPE on f32 accumulators
    const float* sc = (n0 < 2048) ? qsc : ksc;
    const float scale = (n0 < 2048) ? QSCALE : 1.0f;

    float ssp[4][4];
#pragma unroll
    for (int i = 0; i < 4; ++i)
#pragma unroll
      for (int r = 0; r < 4; ++r)
        ssp[i][r] = acc[i][0][r] * acc[i][0][r] + acc[i][1][r] * acc[i][1][r];
#pragma unroll
    for (int o = 1; o < 16; o <<= 1)
#pragma unroll
      for (int i = 0; i < 4; ++i)
#pragma unroll
        for (int r = 0; r < 4; ++r) ssp[i][r] += __shfl_xor(ssp[i][r], o, 64);
    float* red = (float*)smem;           // 256 f32
    float* X = (float*)(smem + 2048);    // [64][132] f32
    if (l15 == 0) {
#pragma unroll
      for (int i = 0; i < 4; ++i)
#pragma unroll
        for (int r = 0; r < 4; ++r) red[w * 64 + i * 16 + quad * 4 + r] = ssp[i][r];
    }
    __syncthreads();
    float rinv[4][4];
#pragma unroll
    for (int i = 0; i < 4; ++i)
#pragma unroll
      for (int r = 0; r < 4; ++r) {
        int row = i * 16 + quad * 4 + r;
        float s = red[row] + red[64 + row] + red[128 + row] + red[192 + row];
        rinv[i][r] = rsqrtf(s * (1.0f / 128.0f) + 1e-6f) * scale;
      }
    float sc0 = sc[colL0], sc1 = sc[colL1];
#pragma unroll
    for (int i = 0; i < 4; ++i)
#pragma unroll
      for (int r = 0; r < 4; ++r) {
        int row = i * 16 + quad * 4 + r;
        X[row * 132 + colL0] = acc[i][0][r] * rinv[i][r] * sc0;
        X[row * 132 + colL1] = acc[i][1][r] * rinv[i][r] * sc1;
      }
    __syncthreads();
    float sgn0 = (colL0 < 64) ? -1.f : 1.f;
    float sgn1 = (colL1 < 64) ? -1.f : 1.f;
#pragma unroll
    for (int i = 0; i < 4; ++i)
#pragma unroll
      for (int r = 0; r < 4; ++r) {
        int row = i * 16 + quad * 4 + r;
        int srw = m0 + row;
        float xn0 = X[row * 132 + colL0], p0 = X[row * 132 + (colL0 ^ 64)];
        float xn1 = X[row * 132 + colL1], p1 = X[row * 132 + (colL1 ^ 64)];
        float v0 = xn0 * cosp[srw * D + colL0] + sgn0 * p0 * sinp[srw * D + colL0];
        float v1 = xn1 * cosp[srw * D + colL1] + sgn1 * p1 * sinp[srw * D + colL1];
        QKV[(size_t)srw * QKVP + n0 + colL0] = f2bf(v0);
        QKV[(size_t)srw * QKVP + n0 + colL1] = f2bf(v1);
      }
  } else {  // V head: write transposed Vt[gd][s] directly
#pragma unroll
    for (int i = 0; i < 4; ++i) {
      int sbase = m0 + i * 16 + quad * 4;
      ushort4 w0, w1;
      w0.x = f2bf(acc[i][0][0]); w0.y = f2bf(acc[i][0][1]);
      w0.z = f2bf(acc[i][0][2]); w0.w = f2bf(acc[i][0][3]);
      w1.x = f2bf(acc[i][1][0]); w1.y = f2bf(acc[i][1][1]);
      w1.z = f2bf(acc[i][1][2]); w1.w = f2bf(acc[i][1][3]);
      *(ushort4*)(Vt + (size_t)(n0 - 2560 + colL0) * S + sbase) = w0;
      *(ushort4*)(Vt + (size_t)(n0 - 2560 + colL1) * S + sbase) = w1;
    }
  }
}

// ------- MFMA GEMM (Wo): BM=64 x BN=128, BK=64, reads-first, XOR swizzle ----
__global__ __launch_bounds__(256) void k_gemm_mfma(const u16* __restrict__ A,
                                                   const u16* __restrict__ BT,
                                                   void* __restrict__ Cout,
                                                   int N, int K, int out_bf16) {
  __shared__ __align__(16) u16 As[2][64 * 64];
  __shared__ __align__(16) u16 Bs[2][128 * 64];
  const int t = threadIdx.x, w = t >> 6, lane = t & 63;
  const int l15 = lane & 15, quad = lane >> 4;
  const int m0 = blockIdx.y * 64, n0 = blockIdx.x * 128;

  const int srow = lane >> 3;                       // 0..7 within issue
  const int schunk = (lane & 7) ^ srow;             // pre-swizzled source chunk
  const u16* Agb = A + (size_t)(m0 + w * 8 + srow) * K + schunk * 8;
  const u16* Bgb = BT + (size_t)(n0 + w * 8 + srow) * K + schunk * 8;

  f32x4 acc[4][2];
#pragma unroll
  for (int i = 0; i < 4; ++i)
#pragma unroll
    for (int j = 0; j < 2; ++j) acc[i][j] = (f32x4){0.f, 0.f, 0.f, 0.f};

  auto STAGE = [&](int k0, int b) {
#pragma unroll
    for (int it = 0; it < 2; ++it)
      gload16(Agb + (size_t)it * 32 * K + k0, &As[b][(w * 8 + it * 32) * 64]);
#pragma unroll
    for (int it = 0; it < 4; ++it)
      gload16(Bgb + (size_t)it * 32 * K + k0, &Bs[b][(w * 8 + it * 32) * 64]);
  };

  STAGE(0, 0);
  __syncthreads();  // buf0 ready
  int cur = 0;
  for (int k0 = 0; k0 < K; k0 += 64) {
    short8 af[4][2], bf[2][2];
#pragma unroll
    for (int k2 = 0; k2 < 2; ++k2) {
      int ch = (k2 * 4 + quad) ^ (l15 & 7);
#pragma unroll
      for (int i = 0; i < 4; ++i)
        af[i][k2] = *(const short8*)&As[cur][(i * 16 + l15) * 64 + ch * 8];
#pragma unroll
      for (int j = 0; j < 2; ++j)
        bf[j][k2] = *(const short8*)&Bs[cur][(w * 32 + j * 16 + l15) * 64 + ch * 8];
    }

    if (k0 + 64 < K) STAGE(k0 + 64, cur ^ 1);  // DMA flies under the MFMAs

#pragma unroll
    for (int k2 = 0; k2 < 2; ++k2)
#pragma unroll
      for (int i = 0; i < 4; ++i)
#pragma unroll
        for (int j = 0; j < 2; ++j)
          acc[i][j] = __builtin_amdgcn_mfma_f32_16x16x32_bf16(af[i][k2], bf[j][k2], acc[i][j], 0, 0, 0);

    __syncthreads();  // drains prefetch + all waves done reading cur
    cur ^= 1;
  }

  if (out_bf16) {
    u16* C = (u16*)Cout;
#pragma unroll
    for (int i = 0; i < 4; ++i)
#pragma unroll
      for (int j = 0; j < 2; ++j) {
        int col = n0 + w * 32 + j * 16 + l15;
#pragma unroll
        for (int r = 0; r < 4; ++r)
          C[(size_t)(m0 + i * 16 + quad * 4 + r) * N + col] = f2bf(acc[i][j][r]);
      }
  } else {
    float* C = (float*)Cout;
#pragma unroll
    for (int i = 0; i < 4; ++i)
#pragma unroll
      for (int j = 0; j < 2; ++j) {
        int col = n0 + w * 32 + j * 16 + l15;
#pragma unroll
        for (int r = 0; r < 4; ++r)
          C[(size_t)(m0 + i * 16 + quad * 4 + r) * N + col] = acc[i][j][r];
      }
  }
}

// ---------------- flash attention (R10-frozen) ------------------------------
#define KP 128   // K LDS row pitch (u16), unpadded (DMA requirement)
#define PTP 72   // P pitch (u16): b64-write / b128-read aligned

__global__ __launch_bounds__(256) void k_flash(const u16* __restrict__ QKV,
                                               const u16* __restrict__ Vt,
                                               u16* __restrict__ O) {
  const int h = blockIdx.y, g = h >> 2;
  const int qt = (h < 8) ? (31 - (int)blockIdx.x) : (int)blockIdx.x;
  const int t = threadIdx.x;
  const int w = t >> 6, lane = t & 63, l15 = lane & 15, quad = lane >> 4;

  __shared__ __align__(16) u16 Klds[2][64 * KP];
  __shared__ __align__(16) u16 Vlds[128 * 64];     // [d][key], XOR-swizzled
  __shared__ __align__(16) u16 Pt[4][16 * PTP];    // [qcol][key] per wave

  const int qbase = qt * 64 + w * 16;
  const int qrow = qbase + l15;

  short8 qf[4];
  {
    const u16* qp = QKV + (size_t)qrow * QKVP + h * D + quad * 8;
#pragma unroll
    for (int c = 0; c < 4; ++c) qf[c] = *(const short8*)(qp + c * 32);
  }

  float m = NEG_INF, l = 0.f;
  f32x4 oacc[8];
#pragma unroll
  for (int nc = 0; nc < 8; ++nc) oacc[nc] = (f32x4){0.f, 0.f, 0.f, 0.f};

  const int nt = qt + 1;
  const int dd = t >> 3, cc = t & 7;  // V staging coords

  auto KLOAD = [&](int j0, int b) {  // DMA 4 rows per wave per issue
#pragma unroll
    for (int it = 0; it < 4; ++it) {
      int rl = w * 16 + it * 4 + quad;                 // tile-local key row
      int gchunk = (lane & 15) ^ (rl & 7);             // source swizzle
      const u16* gp = QKV + (size_t)(j0 + rl) * QKVP + 2048 + g * D + gchunk * 8;
      gload16(gp, &Klds[b][(w * 16 + it * 4) * KP]);
    }
  };
  auto VLOAD = [&](int j0, uint4* vr) {
#pragma unroll
    for (int it = 0; it < 4; ++it)
      vr[it] = *(const uint4*)(Vt + (size_t)(g * D + dd + it * 32) * S + j0 + cc * 8);
  };
  auto VWRITE = [&](uint4* vr) {
#pragma unroll
    for (int it = 0; it < 4; ++it) {
      int d = dd + it * 32;
      *(uint4*)&Vlds[d * 64 + ((cc ^ (d & 7)) * 8)] = vr[it];
    }
  };
  auto QKT = [&](int b, f32x4* sa) {
#pragma unroll
    for (int sub = 0; sub < 4; ++sub) {
      f32x4 acc = {0.f, 0.f, 0.f, 0.f};
#pragma unroll
      for (int c = 0; c < 4; ++c) {
        int ch = (c * 4 + quad) ^ (l15 & 7);  // undo source swizzle
        short8 kf = *(const short8*)&Klds[b][(sub * 16 + l15) * KP + ch * 8];
        acc = __builtin_amdgcn_mfma_f32_16x16x32_bf16(kf, qf[c], acc, 0, 0, 0);
      }
      sa[sub] = acc;
    }
  };
  auto SMPV = [&](int jt, f32x4* sa) {
    const int j0 = jt * 64;
    if (jt == nt - 1) {  // causal mask, diagonal tile only
#pragma unroll
      for (int sub = 0; sub < 4; ++sub) {
        int keyb = j0 + sub * 16 + quad * 4;
#pragma unroll
        for (int r = 0; r < 4; ++r)
          if (keyb + r > qrow) sa[sub][r] = NEG_INF;
      }
    }
    float tmax = sa[0][0];
#pragma unroll
    for (int sub = 0; sub < 4; ++sub)
#pragma unroll
      for (int r = 0; r < 4; ++r) tmax = fmaxf(tmax, sa[sub][r]);
    tmax = fmaxf(tmax, __shfl_xor(tmax, 16, 64));
    tmax = fmaxf(tmax, __shfl_xor(tmax, 32, 64));
    float mn = fmaxf(m, tmax);
    float alpha = exp2_hw(m - mn);
    m = mn;
    float rs = 0.f;
#pragma unroll
    for (int sub = 0; sub < 4; ++sub) {
      float p0 = exp2_hw(sa[sub][0] - m);
      float p1 = exp2_hw(sa[sub][1] - m);
      float p2 = exp2_hw(sa[sub][2] - m);
      float p3 = exp2_hw(sa[sub][3] - m);
      rs += (p0 + p1) + (p2 + p3);
      u32 lo = cvt_pk_bf16(p0, p1);
      u32 hi = cvt_pk_bf16(p2, p3);
      *(uint2*)&Pt[w][l15 * PTP + sub * 16 + quad * 4] = make_uint2(lo, hi);
    }
    rs += __shfl_xor(rs, 16, 64);
    rs += __shfl_xor(rs, 32, 64);
    l = l * alpha + rs;
#pragma unroll
    for (int nc = 0; nc < 8; ++nc) {
      oacc[nc][0] *= alpha; oacc[nc][1] *= alpha;
      oacc[nc][2] *= alpha; oacc[nc][3] *= alpha;
    }
#pragma unroll
    for (int kc = 0; kc < 2; ++kc) {
      short8 pf = *(const short8*)&Pt[w][l15 * PTP + kc * 32 + quad * 8];
#pragma unroll
      for (int nc = 0; nc < 8; ++nc) {
        int d = nc * 16 + l15;
        short8 vf = *(const short8*)&Vlds[d * 64 + (((kc * 4 + quad) ^ (d & 7)) * 8)];
        oacc[nc] = __builtin_amdgcn_mfma_f32_16x16x32_bf16(vf, pf, oacc[nc], 0, 0, 0);
      }
    }
  };

  uint4 vrA[4], vrB[4];
  f32x4 sa[4];
  KLOAD(0, 0);
  VLOAD(0, vrA);
  for (int jt = 0; jt < nt; jt += 2) {
    __syncthreads();                       // drains K(jt) DMA + all VMEM
    VWRITE(vrA);
    __syncthreads();                       // V(jt) visible
    QKT(0, sa);                            // no outstanding VMEM -> no stall
    if (jt + 1 < nt) { KLOAD((jt + 1) * 64, 1); VLOAD((jt + 1) * 64, vrB); }
    SMPV(jt, sa);                          // covers prefetch latency
    if (jt + 1 < nt) {
      __syncthreads();                     // drains K(jt+1)+V(jt+1), covered
      VWRITE(vrB);
      __syncthreads();
      QKT(1, sa);
      if (jt + 2 < nt) { KLOAD((jt + 2) * 64, 0); VLOAD((jt + 2) * 64, vrA); }
      SMPV(jt + 1, sa);
    }
  }

  // ---- epilogue: O[q][d] = O^T / l ----
  float inv = 1.0f / l;
  u16* orow = O + (size_t)qrow * HID + h * D;
#pragma unroll
  for (int nc = 0; nc < 8; ++nc) {
    ushort4 wv;
    wv.x = f2bf(oacc[nc][0] * inv); wv.y = f2bf(oacc[nc][1] * inv);
    wv.z = f2bf(oacc[nc][2] * inv); wv.w = f2bf(oacc[nc][3] * inv);
    *(ushort4*)(orow + nc * 16 + quad * 4) = wv;
  }
}

// ---------------- final RMSNorm over HIDDEN=2048 (bf16 input) ---------------
__device__ __forceinline__ float blockSum256(float v, float* red, int t) {
#pragma unroll
  for (int o = 32; o; o >>= 1) v += __shfl_xor(v, o, 64);
  if ((t & 63) == 0) red[t >> 6] = v;
  __syncthreads();
  v = red[0] + red[1] + red[2] + red[3];
  __syncthreads();
  return v;
}

__global__ __launch_bounds__(256) void k_fnorm(const u16* __restrict__ X,
                                               const float* __restrict__ sc,
                                               float* __restrict__ out) {
  const int s = blockIdx.x, t = threadIdx.x;
  const u16* row = X + (size_t)s * HID + t * 8;
  short8 rv = *(const short8*)row;
  float x[8];
#pragma unroll
  for (int ii = 0; ii < 8; ++ii) x[ii] = bf2f((u16)rv[ii]);
  float ss = 0.f;
#pragma unroll
  for (int ii = 0; ii < 8; ++ii) ss += x[ii] * x[ii];
  __shared__ float red[4];
  float tot = blockSum256(ss, red, t);
  float rinv = rsqrtf(tot * (1.0f / 2048.0f) + 1e-6f);
  float4 s0 = *(const float4*)(sc + t * 8);
  float4 s1 = *(const float4*)(sc + t * 8 + 4);
  float4 w0 = make_float4(x[0] * rinv * s0.x, x[1] * rinv * s0.y,
                          x[2] * rinv * s0.z, x[3] * rinv * s0.w);
  float4 w1 = make_float4(x[4] * rinv * s1.x, x[5] * rinv * s1.y,
                          x[6] * rinv * s1.z, x[7] * rinv * s1.w);
  *(float4*)(out + (size_t)s * HID + t * 8) = w0;
  *(float4*)(out + (size_t)s * HID + t * 8 + 4) = w1;
}

extern "C" void kernel_launch(void* const* d_in, const int* in_sizes, int n_in,
                              void* d_out, int out_size, void* d_ws, size_t ws_size,
                              hipStream_t stream) {
  const float* hidden = (const float*)d_in[0];
  const float* cosp   = (const float*)d_in[1];
  const float* sinp   = (const float*)d_in[2];
  const float* Wq     = (const float*)d_in[3];
  const float* Wk     = (const float*)d_in[4];
  const float* Wv     = (const float*)d_in[5];
  const float* Wo     = (const float*)d_in[6];
  const float* qsc    = (const float*)d_in[7];
  const float* ksc    = (const float*)d_in[8];
  const float* lsc    = (const float*)d_in[9];
  float* out = (float*)d_out;

  char* ws = (char*)d_ws;
  u16*   Hb  = (u16*)(ws);                   // [S][HID] bf16, 8 MiB
  u16*   WT  = (u16*)(ws + (8ull << 20));    // [3072][2048] bf16, 12 MiB
  u16*   An  = (u16*)(ws + (8ull << 20));    // overlays WT (after QKV GEMM)
  u16*   QKV = (u16*)(ws + (20ull << 20));   // [S][3072] bf16, 12 MiB
  u16*   Ob  = (u16*)(ws + (20ull << 20));   // bf16 [S][HID], 8 MiB (overlays QKV)
  u16*   Vtb = (u16*)(ws + (32ull << 20));   // [512][2048] bf16, 2 MiB

  const bool bigws = ws_size >= (43ull << 20);
  // big-ws: WoT gets a dedicated region -> transpose folds into k_pre_all
  // (overlapped), no serial k_transpose launch. small-ws: WoT overlays Hb.
  u16* WoT = bigws ? (u16*)(ws + (34ull << 20)) : (u16*)ws;

  if (bigws) {
    k_pre_all<<<2048 + 1536 + 1024, 256, 0, stream>>>(hidden, Hb, Wq, Wk, Wv, WT, Wo, WoT);
  } else {
    k_pre<<<2048 + 1536, 256, 0, stream>>>(hidden, Hb, Wq, Wk, Wv, WT);
  }
  k_gemm_qkv<<<dim3(24, 32), 256, 0, stream>>>(Hb, WT, QKV, Vtb, qsc, ksc, cosp, sinp);
  if (!bigws) {
    k_transpose<<<dim3(32, 32), 256, 0, stream>>>(Wo, WoT, 2048, 2048);  // Hb dead
  }
  k_flash<<<dim3(32, NH), 256, 0, stream>>>(QKV, Vtb, An);
  k_gemm_mfma<<<dim3(16, 32), 256, 0, stream>>>(An, WoT, Ob, 2048, 2048, 1);
  k_fnorm<<<S, 256, 0, stream>>>(Ob, lsc, out);
}